// Round 11
// baseline (406.066 us; speedup 1.0000x reference)
//
#include <hip/hip_runtime.h>
#include <hip/hip_cooperative_groups.h>

namespace cg = cooperative_groups;

typedef unsigned int   u32;
typedef unsigned short u16;
typedef float f32x16 __attribute__((ext_vector_type(16)));
typedef short s16x8  __attribute__((ext_vector_type(8)));
typedef u32   u32x4  __attribute__((ext_vector_type(4)));
typedef u32   u32x2  __attribute__((ext_vector_type(2)));

#define B_   64
#define P1_  15
#define P2_  14
#define S_   210            // P1*P2 tokens per batch
#define SP_  224            // padded rows (7 strips of 32) for Q/K/V scratch
#define NT_  (B_*S_)        // 13440 tokens
#define E_   512
#define NH_  8
#define HD_  64
#define KSC  0.18033688011112042f   // 0.125 (=64^-0.5) * log2(e)

#define NBLK 256            // cooperative grid: 1 block/CU under EVERY occupancy model
#define TPB  512

// ---------- bf16 helpers ----------
__device__ __forceinline__ u16 f2bf(float f) {
    u32 u = __float_as_uint(f);
    u += 0x7fffu + ((u >> 16) & 1u);      // RNE
    return (u16)(u >> 16);
}
__device__ __forceinline__ float bf2f(u16 h) {
    return __uint_as_float(((u32)h) << 16);
}
__device__ __forceinline__ u32 cvtpk(float lo, float hi) {
    u32 r;
    asm("v_cvt_pk_bf16_f32 %0, %1, %2" : "=v"(r) : "v"(lo), "v"(hi));
    return r;
}

// wave-local LDS fence (all mode_proj exchange is within one wave)
__device__ __forceinline__ void wfence() {
    asm volatile("s_waitcnt lgkmcnt(0)" ::: "memory");
}

// ---------- shared mode-product: y[a,c,d] = ((x ×0 W0) ×1 W1) ×2 W2 + bias ----------
// xs[m0*66 + m1*8 + m2]; t1[a*68 + y*8 + z]; t2[(a*8+c)*9 + z]
// thread t in [0,64): stage1 t=(y,z); stage2 t=(a,z); stage3 t=(a,c)
__device__ __forceinline__ void mode_proj(
        const float* xs, float* t1, float* t2,
        const float* __restrict__ W0, const float* __restrict__ W1,
        const float* __restrict__ W2, const float* __restrict__ bb,
        int t, float* y3)
{
    {
        float xv[8];
        #pragma unroll
        for (int i = 0; i < 8; ++i) xv[i] = xs[i*66 + t];
        #pragma unroll
        for (int a = 0; a < 8; ++a) {
            float acc = 0.f;
            #pragma unroll
            for (int i = 0; i < 8; ++i) acc = fmaf(W0[a*8+i], xv[i], acc);
            t1[a*68 + t] = acc;
        }
    }
    wfence();
    {
        const int a = t >> 3, z = t & 7;
        float yv[8];
        #pragma unroll
        for (int y = 0; y < 8; ++y) yv[y] = t1[a*68 + y*8 + z];
        #pragma unroll
        for (int c = 0; c < 8; ++c) {
            float acc = 0.f;
            #pragma unroll
            for (int y = 0; y < 8; ++y) acc = fmaf(W1[c*8+y], yv[y], acc);
            t2[(a*8 + c)*9 + z] = acc;
        }
    }
    wfence();
    {
        float zv[8];
        #pragma unroll
        for (int z = 0; z < 8; ++z) zv[z] = t2[t*9 + z];
        #pragma unroll
        for (int d = 0; d < 8; ++d) {
            float acc = bb[t*8 + d];
            #pragma unroll
            for (int z = 0; z < 8; ++z) acc = fmaf(W2[d*8+z], zv[z], acc);
            y3[d] = acc;
        }
    }
    wfence();   // t1/t2 reusable by next call from this wave
}

struct KParams {
    const float *x;
    const float *Wq0, *Wq1, *Wq2, *bq;
    const float *Wk0, *Wk1, *Wk2, *bk;
    const float *Wv0, *Wv1, *Wv2, *bv;
    const float *Wo0, *Wo1, *Wo2, *bo;
    u16 *Qs, *Ks, *Vs, *Os;
    float *out;
};

// LDS layout (phase union, 59392 B):
//  proj phases: xs[8][528] | t1[8][544] | t2[8][576]   (52736 B)
//  attn phase : Kl[224*64] | Vt[64*232] | invl[8*32]   (59392 B)

__global__ __launch_bounds__(TPB, 4) void k_fused(KParams p)
{
    __shared__ __align__(16) char smem[59392];
    cg::grid_group grid = cg::this_grid();

    const int bid  = blockIdx.x;
    const int tid  = threadIdx.x;
    const int w    = tid >> 6;
    const int t    = tid & 63;

    // ================= phase 1: QKV projection (7 sweeps x 2048 tokens) =================
    {
        float* xs = (float*)smem;                  // [8][528]
        float* t1 = (float*)(smem + 16896);        // [8][544]
        float* t2 = (float*)(smem + 34304);        // [8][576]
        const int a  = t >> 3, c = t & 7;
        const int x_ = a >> 1, h1 = a & 1;
        const int y_ = c >> 1, h2 = c & 1;

        for (int it = 0; it < 7; ++it) {
            const int tok = it*2048 + bid*8 + w;
            if (tok >= NT_) break;
            const int b = tok / S_;
            const int s = tok - b * S_;

            const float* xp = p.x + (size_t)tok * E_;
            #pragma unroll
            for (int k4 = 0; k4 < 2; ++k4) {
                const float4 vv = *reinterpret_cast<const float4*>(xp + k4*256 + t*4);
                const int m0 = k4*4 + (t >> 4);
                const int in = (t*4) & 63;
                xs[w*528 + m0*66 + in + 0] = vv.x;
                xs[w*528 + m0*66 + in + 1] = vv.y;
                xs[w*528 + m0*66 + in + 2] = vv.z;
                xs[w*528 + m0*66 + in + 3] = vv.w;
            }
            wfence();

            float y3[8];
            mode_proj(xs + w*528, t1 + w*544, t2 + w*576, p.Wq0, p.Wq1, p.Wq2, p.bq, t, y3);
            #pragma unroll
            for (int h3 = 0; h3 < 2; ++h3) {
                const int h = (((h1 << 1) | h2) << 1) | h3;
                u32x2 pk;
                pk[0] = cvtpk(y3[0 + h3], y3[2 + h3]);
                pk[1] = cvtpk(y3[4 + h3], y3[6 + h3]);
                *reinterpret_cast<u32x2*>(
                    p.Qs + ((size_t)(b*NH_ + h)*SP_ + s)*HD_ + (x_*16 + y_*4)) = pk;
            }
            mode_proj(xs + w*528, t1 + w*544, t2 + w*576, p.Wk0, p.Wk1, p.Wk2, p.bk, t, y3);
            #pragma unroll
            for (int h3 = 0; h3 < 2; ++h3) {
                const int h = (((h1 << 1) | h2) << 1) | h3;
                u32x2 pk;
                pk[0] = cvtpk(y3[0 + h3], y3[2 + h3]);
                pk[1] = cvtpk(y3[4 + h3], y3[6 + h3]);
                *reinterpret_cast<u32x2*>(
                    p.Ks + ((size_t)(b*NH_ + h)*SP_ + s)*HD_ + (x_*16 + y_*4)) = pk;
            }
            mode_proj(xs + w*528, t1 + w*544, t2 + w*576, p.Wv0, p.Wv1, p.Wv2, p.bv, t, y3);
            #pragma unroll
            for (int h3 = 0; h3 < 2; ++h3) {
                const int h = (((h1 << 1) | h2) << 1) | h3;
                u32x2 pk;
                pk[0] = cvtpk(y3[0 + h3], y3[2 + h3]);
                pk[1] = cvtpk(y3[4 + h3], y3[6 + h3]);
                *reinterpret_cast<u32x2*>(
                    p.Vs + ((size_t)(b*NH_ + h)*SP_ + s)*HD_ + (x_*16 + y_*4)) = pk;
            }
        }
    }

    __threadfence();
    grid.sync();

    // ================= phase 2: MFMA attention, 2 x (b,h) per block =================
    {
        u16*   Kl   = (u16*)smem;                  // [224*64] 16B-block XOR-swizzled
        u16*   Vt   = (u16*)(smem + 28672);        // [64][232] transposed V
        float* invl = (float*)(smem + 58368);      // [8*32]

        const int lane = tid & 63;
        const int l31  = lane & 31;
        const int hi   = lane >> 5;
        const int strip = (w < 7) ? w : 6;

        for (int rep = 0; rep < 2; ++rep) {
            if (rep) __syncthreads();              // all waves done reading LDS of rep 0
            const int bh = bid + rep*256;
            const u16* Qg = p.Qs + (size_t)bh*SP_*HD_;
            const u16* Kg = p.Ks + (size_t)bh*SP_*HD_;
            const u16* Vg = p.Vs + (size_t)bh*SP_*HD_;

            // Q B-frags: issue EARLY so VMEM latency overlaps K/V staging
            const u16* qb = Qg + (size_t)(strip*32 + l31)*64 + hi*8;
            const s16x8 qf0 = *(const s16x8*)(qb +  0);
            const s16x8 qf1 = *(const s16x8*)(qb + 16);
            const s16x8 qf2 = *(const s16x8*)(qb + 32);
            const s16x8 qf3 = *(const s16x8*)(qb + 48);

            // stage K (swizzled 16B blocks)
            #pragma unroll
            for (int i = 0; i < 4; ++i) {
                int sIdx = i*512 + tid;
                if (sIdx < 1792) {
                    int row = sIdx >> 3, cc = sIdx & 7;
                    u32x4 d = *(const u32x4*)(Kg + sIdx*8);
                    *(u32x4*)&Kl[row*64 + (cc ^ (row & 7))*8] = d;
                }
            }
            // stage V transposed
            if (tid < 448) {
                int tokg = tid >> 3, dg = tid & 7;
                int t0 = tokg*4, d0 = dg*8;
                u32x4 r0 = *(const u32x4*)(Vg + (size_t)(t0+0)*64 + d0);
                u32x4 r1 = *(const u32x4*)(Vg + (size_t)(t0+1)*64 + d0);
                u32x4 r2 = *(const u32x4*)(Vg + (size_t)(t0+2)*64 + d0);
                u32x4 r3 = *(const u32x4*)(Vg + (size_t)(t0+3)*64 + d0);
                #pragma unroll
                for (int j = 0; j < 8; ++j) {
                    u32 sel = (j & 1) ? 0x07060302u : 0x05040100u;
                    u32 lo  = __builtin_amdgcn_perm(r1[j>>1], r0[j>>1], sel);
                    u32 hi2 = __builtin_amdgcn_perm(r3[j>>1], r2[j>>1], sel);
                    *(u32x2*)&Vt[(d0+j)*232 + t0] = (u32x2){lo, hi2};
                }
            }
            __syncthreads();

            if (w < 7) {
                f32x16 oacc0 = {}, oacc1 = {};
                float  psum  = 0.f;
                const int swz = l31 & 7;

                #pragma unroll
                for (int kt = 0; kt < 7; ++kt) {
                    const u16* kbase = &Kl[(kt*32 + l31)*64];
                    f32x16 sacc = {};
                    s16x8 kf0 = *(const s16x8*)(kbase + ((0 + hi) ^ swz)*8);
                    s16x8 kf1 = *(const s16x8*)(kbase + ((2 + hi) ^ swz)*8);
                    s16x8 kf2 = *(const s16x8*)(kbase + ((4 + hi) ^ swz)*8);
                    s16x8 kf3 = *(const s16x8*)(kbase + ((6 + hi) ^ swz)*8);
                    __builtin_amdgcn_s_setprio(1);
                    sacc = __builtin_amdgcn_mfma_f32_32x32x16_bf16(kf0, qf0, sacc, 0, 0, 0);
                    sacc = __builtin_amdgcn_mfma_f32_32x32x16_bf16(kf1, qf1, sacc, 0, 0, 0);
                    sacc = __builtin_amdgcn_mfma_f32_32x32x16_bf16(kf2, qf2, sacc, 0, 0, 0);
                    sacc = __builtin_amdgcn_mfma_f32_32x32x16_bf16(kf3, qf3, sacc, 0, 0, 0);
                    __builtin_amdgcn_s_setprio(0);

                    float pr[16];
                    #pragma unroll
                    for (int r = 0; r < 16; ++r) pr[r] = exp2f(sacc[r] * KSC);
                    if (kt == 6) {            // keys 192+krow valid iff krow < 18
                        const float hm = hi ? 0.f : 1.f;
                        pr[8] *= hm; pr[9] *= hm;
                        pr[10] = 0.f; pr[11] = 0.f; pr[12] = 0.f; pr[13] = 0.f; pr[14] = 0.f; pr[15] = 0.f;
                    }
                    #pragma unroll
                    for (int r = 0; r < 16; ++r) psum += pr[r];

                    u32 c0, c1, c2, c3, c4, c5, c6, c7;
                    asm("v_cvt_pk_bf16_f32 %0, %1, %2" : "=v"(c0) : "v"(pr[0]),  "v"(pr[1]));
                    asm("v_cvt_pk_bf16_f32 %0, %1, %2" : "=v"(c1) : "v"(pr[2]),  "v"(pr[3]));
                    asm("v_cvt_pk_bf16_f32 %0, %1, %2" : "=v"(c2) : "v"(pr[4]),  "v"(pr[5]));
                    asm("v_cvt_pk_bf16_f32 %0, %1, %2" : "=v"(c3) : "v"(pr[6]),  "v"(pr[7]));
                    asm("v_cvt_pk_bf16_f32 %0, %1, %2" : "=v"(c4) : "v"(pr[8]),  "v"(pr[9]));
                    asm("v_cvt_pk_bf16_f32 %0, %1, %2" : "=v"(c5) : "v"(pr[10]), "v"(pr[11]));
                    asm("v_cvt_pk_bf16_f32 %0, %1, %2" : "=v"(c6) : "v"(pr[12]), "v"(pr[13]));
                    asm("v_cvt_pk_bf16_f32 %0, %1, %2" : "=v"(c7) : "v"(pr[14]), "v"(pr[15]));
                    asm("v_permlane32_swap_b32 %0, %1" : "+v"(c0), "+v"(c2));
                    asm("v_permlane32_swap_b32 %0, %1" : "+v"(c1), "+v"(c3));
                    asm("v_permlane32_swap_b32 %0, %1" : "+v"(c4), "+v"(c6));
                    asm("v_permlane32_swap_b32 %0, %1" : "+v"(c5), "+v"(c7));
                    const s16x8 pf0 = __builtin_bit_cast(s16x8, (u32x4){c0, c1, c2, c3});
                    const s16x8 pf1 = __builtin_bit_cast(s16x8, (u32x4){c4, c5, c6, c7});

                    const u16* vb = &Vt[kt*32 + hi*8];
                    s16x8 vf0 = *(const s16x8*)(vb + (0*32 + l31)*232 +  0);
                    s16x8 vf1 = *(const s16x8*)(vb + (0*32 + l31)*232 + 16);
                    s16x8 vf2 = *(const s16x8*)(vb + (1*32 + l31)*232 +  0);
                    s16x8 vf3 = *(const s16x8*)(vb + (1*32 + l31)*232 + 16);
                    __builtin_amdgcn_s_setprio(1);
                    oacc0 = __builtin_amdgcn_mfma_f32_32x32x16_bf16(pf0, vf0, oacc0, 0, 0, 0);
                    oacc0 = __builtin_amdgcn_mfma_f32_32x32x16_bf16(pf1, vf1, oacc0, 0, 0, 0);
                    oacc1 = __builtin_amdgcn_mfma_f32_32x32x16_bf16(pf0, vf2, oacc1, 0, 0, 0);
                    oacc1 = __builtin_amdgcn_mfma_f32_32x32x16_bf16(pf1, vf3, oacc1, 0, 0, 0);
                    __builtin_amdgcn_s_setprio(0);
                }

                float tot = psum + __shfl_xor(psum, 32, 64);
                invl[w*32 + l31] = 1.0f / tot;
                wfence();

                u16* Ob = p.Os + ((size_t)bh*S_ + strip*32)*HD_;
                #pragma unroll
                for (int r = 0; r < 16; ++r) {
                    const int q = (r & 3) + 8*(r >> 2) + 4*hi;
                    if (strip == 6 && q >= 18) continue;        // token >= 210
                    const float iv = invl[w*32 + q];
                    Ob[(size_t)q*64 + l31]      = f2bf(oacc0[r] * iv);
                    Ob[(size_t)q*64 + 32 + l31] = f2bf(oacc1[r] * iv);
                }
            }
        }
    }

    __threadfence();
    grid.sync();

    // ================= phase 3: output projection (7 sweeps x 2048 tokens) =================
    {
        float* xs = (float*)smem;                  // [8][528]
        float* t1 = (float*)(smem + 16896);        // [8][544]
        float* t2 = (float*)(smem + 34304);        // [8][576]
        const int a  = t >> 3, c = t & 7;
        const int x_ = a >> 1, h1 = a & 1;
        const int y_ = c >> 1, h2 = c & 1;

        for (int it = 0; it < 7; ++it) {
            const int tok = it*2048 + bid*8 + w;
            if (tok >= NT_) break;
            const int b = tok / S_;
            const int s = tok - b * S_;

            #pragma unroll
            for (int h3 = 0; h3 < 2; ++h3) {
                const int h = (((h1 << 1) | h2) << 1) | h3;
                const ushort4 v = *reinterpret_cast<const ushort4*>(
                    p.Os + ((size_t)(b*NH_ + h)*S_ + s)*HD_ + (x_*16 + y_*4));
                xs[w*528 + a*66 + c*8 + 0 + h3] = bf2f(v.x);
                xs[w*528 + a*66 + c*8 + 2 + h3] = bf2f(v.y);
                xs[w*528 + a*66 + c*8 + 4 + h3] = bf2f(v.z);
                xs[w*528 + a*66 + c*8 + 6 + h3] = bf2f(v.w);
            }
            wfence();

            float y3[8];
            mode_proj(xs + w*528, t1 + w*544, t2 + w*576, p.Wo0, p.Wo1, p.Wo2, p.bo, t, y3);

            float4* op = reinterpret_cast<float4*>(p.out + (size_t)tok * E_ + t * 8);
            float4 u0, u1;
            u0.x = y3[0]; u0.y = y3[1]; u0.z = y3[2]; u0.w = y3[3];
            u1.x = y3[4]; u1.y = y3[5]; u1.z = y3[6]; u1.w = y3[7];
            op[0] = u0;
            op[1] = u1;
        }
    }
}

extern "C" void kernel_launch(void* const* d_in, const int* in_sizes, int n_in,
                              void* d_out, int out_size, void* d_ws, size_t ws_size,
                              hipStream_t stream)
{
    const size_t TP = (size_t)B_ * NH_ * SP_ * HD_;   // padded Q/K/V tensors

    KParams p;
    p.x   = (const float*)d_in[0];
    p.Wq0 = (const float*)d_in[1];  p.Wq1 = (const float*)d_in[2];
    p.Wq2 = (const float*)d_in[3];  p.bq  = (const float*)d_in[4];
    p.Wk0 = (const float*)d_in[5];  p.Wk1 = (const float*)d_in[6];
    p.Wk2 = (const float*)d_in[7];  p.bk  = (const float*)d_in[8];
    p.Wv0 = (const float*)d_in[9];  p.Wv1 = (const float*)d_in[10];
    p.Wv2 = (const float*)d_in[11]; p.bv  = (const float*)d_in[12];
    p.Wo0 = (const float*)d_in[13]; p.Wo1 = (const float*)d_in[14];
    p.Wo2 = (const float*)d_in[15]; p.bo  = (const float*)d_in[16];
    p.Qs  = (u16*)d_ws;
    p.Ks  = p.Qs + TP;
    p.Vs  = p.Ks + TP;
    p.Os  = p.Vs + TP;
    p.out = (float*)d_out;

    void* args[] = { &p };
    hipLaunchCooperativeKernel((const void*)k_fused,
                               dim3(NBLK), dim3(TPB), args, 0, stream);
}